// Round 5
// baseline (967.642 us; speedup 1.0000x reference)
//
#include <hip/hip_runtime.h>
#include <stdint.h>

#define NROWS 4000
#define NCOLS 30000
#define NQ4   1875          // NCOLS / 16: groups of 4 float4 (16 elems)
#define BATCH 8
#define SPANS 500           // LEN_S * LEN_E
#define LEN_E_ 10
#define KLOG2E 14.4269504088896340736f   // (1/T) * log2(e), T = 0.1

typedef float f32x4 __attribute__((ext_vector_type(4)));

__device__ __forceinline__ float fexp2(float x) {
    return __builtin_amdgcn_exp2f(x);    // raw v_exp_f32; underflow->0 is fine
}

// Single fused kernel.
//  - 4000 blocks, one row each: soft-min (fixed ref m=0, branch-free) +
//    argmin + celu threshold; raw (unmasked) score -> out[32+row],
//    argmin -> ws.
//  - last block to finish (atomic counter) becomes the finale: detects the
//    'viable' element size ONCE, masks the 4000 scores, then runs the 8
//    per-batch span softmaxes. Runs in the tail shadow while the rest of
//    the GPU is already idle.
__global__ __launch_bounds__(256) void extract_fused(
    const float* __restrict__ ed, const void* __restrict__ viable,
    float* __restrict__ out, int* __restrict__ amin,
    unsigned int* __restrict__ cnt) {
    const int row = blockIdx.x;
    const int tid = threadIdx.x;

    const f32x4* __restrict__ rp =
        (const f32x4*)(ed + (size_t)row * NCOLS);   // 120000 B, 16B aligned

    float Z = 0.f, S = 0.f, mv = INFINITY;
    int   vi = 0;

    for (int j = tid; j < NQ4; j += 256) {
        f32x4 vv[4];
        vv[0] = rp[4 * j + 0];
        vv[1] = rp[4 * j + 1];
        vv[2] = rp[4 * j + 2];
        vv[3] = rp[4 * j + 3];
        const int base = j << 4;
#pragma unroll
        for (int q = 0; q < 4; ++q) {
#pragma unroll
            for (int c = 0; c < 4; ++c) {
                float x = vv[q][c];
                float e = fexp2(x * -KLOG2E);
                Z += e;
                S = fmaf(x, e, S);
                bool lt = x < mv;              // cndmask pair, no branch
                mv = lt ? x : mv;
                vi = lt ? (base + q * 4 + c) : vi;
            }
        }
    }

    // wave shuffle reduce (sum Z,S; lexicographic min (mv,vi))
#pragma unroll
    for (int off = 32; off > 0; off >>= 1) {
        Z += __shfl_down(Z, off);
        S += __shfl_down(S, off);
        float ov = __shfl_down(mv, off);
        int   oi = __shfl_down(vi, off);
        if (ov < mv || (ov == mv && oi < vi)) { mv = ov; vi = oi; }
    }
    __shared__ float wZ[4], wS[4], wM[4];
    __shared__ int   wI[4];
    if ((tid & 63) == 0) {
        int w = tid >> 6;
        wZ[w] = Z; wS[w] = S; wM[w] = mv; wI[w] = vi;
    }
    __syncthreads();

    if (tid == 0) {
        float Zt = 0.f, St = 0.f, m = INFINITY;
        int ii = 0;
#pragma unroll
        for (int w = 0; w < 4; ++w) {
            Zt += wZ[w]; St += wS[w];
            if (wM[w] < m || (wM[w] == m && wI[w] < ii)) { m = wM[w]; ii = wI[w]; }
        }
        float ed_v  = St / Zt;                 // soft-min value
        float z     = 1.f - 40.f * ed_v;       // 1 - 2x/thresh, thresh=0.05
        float celu  = z > 0.f ? z : expm1f(z);
        amin[row]     = ii;
        out[32 + row] = 0.5f * (celu + 1.f);   // raw score; finale masks
    }

    // ---- last-block election ------------------------------------------------
    __shared__ int s_last;
    __threadfence();                           // release our stores
    if (tid == 0) {
        unsigned int old = atomicAdd(cnt, 1u);
        s_last = (old == NROWS - 1);
    }
    __syncthreads();
    if (!s_last) return;
    __threadfence();                           // acquire all blocks' stores

    // ---- finale: detect 'viable' esz, mask scores, 8 span softmaxes --------
    // esz detection (1 / 4 / 8 bytes): nonzero bytes in first 2048 B.
    // u8 ~1024, f32 ~512, i32 ~256, i64 ~128 -> thresholds 800 / 192.
    __shared__ int s_esz;
    if (tid < 64) {
        const uint8_t* p = (const uint8_t*)viable;
        int c = 0;
#pragma unroll
        for (int k = 0; k < 32; ++k) c += (p[tid * 32 + k] != 0);
#pragma unroll
        for (int off = 32; off > 0; off >>= 1) c += __shfl_down(c, off);
        if (tid == 0) s_esz = (c >= 800) ? 1 : (c >= 192 ? 4 : 8);
    }
    __syncthreads();
    const int esz = s_esz;

    // mask pass: out[32+r] = viable ? raw : 0
    for (int r = tid; r < NROWS; r += 256) {
        float s = out[32 + r];
        bool viab;
        if (esz == 1)      viab = ((const uint8_t*)viable)[r] != 0;
        else if (esz == 4) viab = ((const uint32_t*)viable)[r] != 0u;
        else               viab = ((const unsigned long long*)viable)[r] != 0ull;
        out[32 + r] = viab ? s : 0.f;
    }
    __threadfence_block();
    __syncthreads();

    __shared__ float sv[256], sZ[256], sS[256];
    __shared__ int   si[256];

    for (int b = 0; b < BATCH; ++b) {
        const float* __restrict__ sc = out + 32 + b * SPANS;

        // phase 1: max + argmax (first occurrence)
        float mx = -INFINITY; int ai = 0;
        for (int j = tid; j < SPANS; j += 256) {
            float x = sc[j];
            if (x > mx) { mx = x; ai = j; }
        }
        sv[tid] = mx; si[tid] = ai;
        __syncthreads();
        for (int off = 128; off > 0; off >>= 1) {
            if (tid < off) {
                float v2 = sv[tid+off]; int i2 = si[tid+off];
                if (v2 > sv[tid] || (v2 == sv[tid] && i2 < si[tid])) {
                    sv[tid] = v2; si[tid] = i2;
                }
            }
            __syncthreads();
        }
        const float M    = sv[0];
        const int   best = si[0];
        __syncthreads();

        // phase 2: softmax-weighted sum over the 500 spans
        float Zb = 0.f, Sb = 0.f;
        for (int j = tid; j < SPANS; j += 256) {
            float x = sc[j];
            float e = fexp2((x - M) * KLOG2E);
            Zb += e;
            Sb = fmaf(x, e, Sb);
        }
        sZ[tid] = Zb; sS[tid] = Sb;
        __syncthreads();
        for (int off = 128; off > 0; off >>= 1) {
            if (tid < off) { sZ[tid] += sZ[tid+off]; sS[tid] += sS[tid+off]; }
            __syncthreads();
        }

        if (tid == 0) {
            int start = best / LEN_E_;
            int len   = best % LEN_E_;
            out[b]      = sS[0] / sZ[0];
            out[8 + b]  = (float)start;
            out[16 + b] = (float)(start + len);
            // viable slots have strictly positive scores; non-viable are 0
            out[24 + b] = (M > 0.f) ? (float)amin[b * SPANS + best] : -1.f;
        }
        __syncthreads();
    }
}

extern "C" void kernel_launch(void* const* d_in, const int* in_sizes, int n_in,
                              void* d_out, int out_size, void* d_ws,
                              size_t ws_size, hipStream_t stream) {
    const float* ed     = (const float*)d_in[0];
    const void*  viable = d_in[4];   // ed_dist, bi, lsi, lei, viable
    float* out  = (float*)d_out;
    int*   amin = (int*)d_ws;                          // 16000 B
    unsigned int* cnt = (unsigned int*)((char*)d_ws + 16384);

    hipMemsetAsync(cnt, 0, sizeof(unsigned int), stream);
    hipLaunchKernelGGL(extract_fused, dim3(NROWS), dim3(256), 0, stream,
                       ed, viable, out, amin, cnt);
}

// Round 6
// 91.688 us; speedup vs baseline: 10.5536x; 10.5536x over previous
//
#include <hip/hip_runtime.h>
#include <stdint.h>

#define NROWS 4000
#define NCOLS 30000
#define NQ4   1875          // NCOLS / 16 (four float4 per thread-iter)
#define BATCH 8
#define SPANS 500           // LEN_S * LEN_E
#define LEN_E_ 10
#define KLOG2E 14.4269504088896340736f   // (1/T) * log2(e), T = 0.1

__device__ __forceinline__ float fexp2(float x) {
    return __builtin_amdgcn_exp2f(x);    // raw v_exp_f32; underflow->0 is fine
}

// ---- detect element size of the 'viable' bool array (1 / 4 / 8 bytes) ----
// Counts nonzero bytes in the first 2048 bytes. Expected nonzero-byte counts:
// u8 ~1024, f32 ~512, i32 ~256, i64 ~128 -> thresholds 800 / 192.
__device__ __forceinline__ int detect_elem_bytes(const uint8_t* __restrict__ p,
                                                 int tid) {
    __shared__ int s_count;
    if (tid == 0) s_count = 0;
    __syncthreads();
    int c = 0;
#pragma unroll
    for (int k = 0; k < 8; ++k) c += (p[tid * 8 + k] != 0);
#pragma unroll
    for (int off = 32; off > 0; off >>= 1) c += __shfl_down(c, off);
    if ((tid & 63) == 0) atomicAdd(&s_count, c);
    __syncthreads();
    int cnt = s_count;
    return cnt >= 800 ? 1 : (cnt >= 192 ? 4 : 8);
}

__device__ __forceinline__ bool viable_at(const void* __restrict__ p, int esz,
                                          int i) {
    if (esz == 1) return ((const uint8_t*)p)[i] != 0;
    if (esz == 4) return ((const uint32_t*)p)[i] != 0u;
    return ((const unsigned long long*)p)[i] != 0ull;
}

// ---- kernel 1: per-row soft-min (fixed ref m=0) + argmin + threshold ------
// ed >= 0, so e = exp2(-x*K) <= 1: no overflow, no rescale, no branch.
// Per-thread element order is monotonic in index (16 consecutive elems/iter),
// so strict < tracking + lexicographic (value,index) reduce = jnp.argmin
// first-occurrence semantics exactly.
__global__ __launch_bounds__(256) void softmin_rows(
    const float* __restrict__ ed, const void* __restrict__ viable,
    float* __restrict__ out, int* __restrict__ amin) {
    const int row = blockIdx.x;
    const int tid = threadIdx.x;

    const int esz = detect_elem_bytes((const uint8_t*)viable, tid);

    const float4* __restrict__ rp =
        (const float4*)(ed + (size_t)row * NCOLS);   // 120000 B, 16B aligned

    float Z = 0.f, S = 0.f, mv = INFINITY;
    int   vi = 0;

#pragma unroll 2
    for (int j = tid; j < NQ4; j += 256) {
        float4 vv[4];
        vv[0] = rp[4 * j + 0];
        vv[1] = rp[4 * j + 1];
        vv[2] = rp[4 * j + 2];
        vv[3] = rp[4 * j + 3];
        const int base = j << 4;
#pragma unroll
        for (int q = 0; q < 4; ++q) {
#pragma unroll
            for (int c = 0; c < 4; ++c) {
                float x = (&vv[q].x)[c];
                float e = fexp2(x * -KLOG2E);
                Z += e;
                S = fmaf(x, e, S);
                bool lt = x < mv;              // cndmask pair, no branch
                mv = lt ? x : mv;
                vi = lt ? (base + q * 4 + c) : vi;
            }
        }
    }

    // wave shuffle reduce (sum Z,S; lexicographic min (mv,vi))
#pragma unroll
    for (int off = 32; off > 0; off >>= 1) {
        Z += __shfl_down(Z, off);
        S += __shfl_down(S, off);
        float ov = __shfl_down(mv, off);
        int   oi = __shfl_down(vi, off);
        if (ov < mv || (ov == mv && oi < vi)) { mv = ov; vi = oi; }
    }
    __shared__ float wZ[4], wS[4], wM[4];
    __shared__ int   wI[4];
    if ((tid & 63) == 0) {
        int w = tid >> 6;
        wZ[w] = Z; wS[w] = S; wM[w] = mv; wI[w] = vi;
    }
    __syncthreads();

    if (tid == 0) {
        float Zt = 0.f, St = 0.f, m = INFINITY;
        int ii = 0;
#pragma unroll
        for (int w = 0; w < 4; ++w) {
            Zt += wZ[w]; St += wS[w];
            if (wM[w] < m || (wM[w] == m && wI[w] < ii)) { m = wM[w]; ii = wI[w]; }
        }
        float ed_v  = St / Zt;                 // soft-min value
        float z     = 1.f - 40.f * ed_v;       // 1 - 2x/thresh, thresh=0.05
        float celu  = z > 0.f ? z : expm1f(z);
        float score = 0.5f * (celu + 1.f);
        amin[row]     = ii;
        out[32 + row] = viable_at(viable, esz, row) ? score : 0.f;
    }
}

// ---- kernel 2: per-batch soft-max over 500 span scores + outputs ----------
__global__ __launch_bounds__(256) void span_softmax(
    const int* __restrict__ amin, float* __restrict__ out) {
    const int b   = blockIdx.x;
    const int tid = threadIdx.x;
    const float* __restrict__ sc = out + 32 + b * SPANS;

    __shared__ float sv[256];
    __shared__ int   si[256];

    // phase 1: max + argmax (first occurrence)
    float mx = -INFINITY; int ai = 0;
    for (int j = tid; j < SPANS; j += 256) {
        float x = sc[j];
        if (x > mx) { mx = x; ai = j; }
    }
    sv[tid] = mx; si[tid] = ai;
    __syncthreads();
    for (int off = 128; off > 0; off >>= 1) {
        if (tid < off) {
            float v2 = sv[tid+off]; int i2 = si[tid+off];
            if (v2 > sv[tid] || (v2 == sv[tid] && i2 < si[tid])) {
                sv[tid] = v2; si[tid] = i2;
            }
        }
        __syncthreads();
    }
    const float M    = sv[0];
    const int   best = si[0];
    __syncthreads();

    // phase 2: softmax-weighted sum over the 500 spans
    float Z = 0.f, S = 0.f;
    for (int j = tid; j < SPANS; j += 256) {
        float x = sc[j];
        float e = fexp2((x - M) * KLOG2E);
        Z += e;
        S = fmaf(x, e, S);
    }
    __shared__ float sZ[256], sS[256];
    sZ[tid] = Z; sS[tid] = S;
    __syncthreads();
    for (int off = 128; off > 0; off >>= 1) {
        if (tid < off) { sZ[tid] += sZ[tid+off]; sS[tid] += sS[tid+off]; }
        __syncthreads();
    }

    if (tid == 0) {
        int start = best / LEN_E_;
        int len   = best % LEN_E_;
        out[b]      = sS[0] / sZ[0];
        out[8 + b]  = (float)start;
        out[16 + b] = (float)(start + len);
        // viable slots have strictly positive scores; non-viable are exactly 0
        out[24 + b] = (M > 0.f) ? (float)amin[b * SPANS + best] : -1.f;
    }
}

extern "C" void kernel_launch(void* const* d_in, const int* in_sizes, int n_in,
                              void* d_out, int out_size, void* d_ws,
                              size_t ws_size, hipStream_t stream) {
    const float* ed     = (const float*)d_in[0];
    const void*  viable = d_in[4];   // ed_dist, bi, lsi, lei, viable
    float* out  = (float*)d_out;
    int*   amin = (int*)d_ws;        // 4000 ints = 16 KB scratch

    hipLaunchKernelGGL(softmin_rows, dim3(NROWS), dim3(256), 0, stream,
                       ed, viable, out, amin);
    hipLaunchKernelGGL(span_softmax, dim3(BATCH), dim3(256), 0, stream,
                       amin, out);
}